// Round 4
// baseline (1035.197 us; speedup 1.0000x reference)
//
#include <hip/hip_runtime.h>

#define TT 512

typedef float f32x4 __attribute__((ext_vector_type(4)));

template<int CTRL>
__device__ __forceinline__ float dpp_mov(float v) {
    return __int_as_float(__builtin_amdgcn_mov_dpp(__float_as_int(v), CTRL, 0xF, 0xF, true));
}
__device__ __forceinline__ float swz_xor4(float v) {
    return __int_as_float(__builtin_amdgcn_ds_swizzle(__float_as_int(v), 0x101F));
}

#define LOG2E 1.4426950408889634f
#define NEG2LOG2E -2.8853900817779268f

// 8-slot select-free xor-merge (3 lane-bits) — used by enc.
__device__ __forceinline__ float merge8(float* s) {
    s[0] += dpp_mov<0xB1>(s[4]);
    s[1] += dpp_mov<0xB1>(s[5]);
    s[2] += dpp_mov<0xB1>(s[6]);
    s[3] += dpp_mov<0xB1>(s[7]);
    s[0] += dpp_mov<0x4E>(s[2]);
    s[1] += dpp_mov<0x4E>(s[3]);
    return s[0] + swz_xor4(s[1]);
}

// ---------------------------------------------------------------------------
// Decoder (REWRITTEN): 256 blocks x 512 threads (8 waves, 2/SIMD), 2 rows.
// tid = gg*4 + q; gg = j in [0,128), q in [0,4) = 32-float k-slice.
// Lane bits q0,q1 drive a 2-level quad_perm-only merge (no ds_swizzle on the
// critical path). 8 slots: s[2m]=row0, s[2m+1]=row1, gate of slot-pair m is
// (m ^ msk2), msk2 = 2*q0+q1 = final gate owner. After merging each lane
// holds BOTH rows' z for its gate. Weights: 4 gate-rows x 32 k = 32 f32x4 =
// 128 VGPR, zero block-level duplication (512 thr x 128 = |Whh|).
// LDS h: slice stride 36 floats, row stride 148 -> <=2-way bank alias (free).
// Per wave per step: 16 ds_read_b128, 256 v_fmac_f32, 6-op merge, 8 dpp
// gate broadcasts, 2 gate tails, 1 barrier. Per-SIMD issue ~1240 cyc vs
// 1384 for the 1024-thread shape; spine loses the swizzle latency.
// ---------------------------------------------------------------------------
__global__ __launch_bounds__(512, 2)
void dec_kernel(const float* __restrict__ h_enc,  // [B,64]
                const float* __restrict__ Wih,    // [512,64]
                const float* __restrict__ Whh,    // [512,128]
                const float* __restrict__ bias,   // [512]
                float* __restrict__ out)          // [B,T,128]
{
    const int tid = threadIdx.x;
    const int gg  = tid >> 2;               // j in [0,128)
    const int q   = tid & 3;                // k-slice / merge lane
    const int q0 = q & 1, q1 = (q >> 1) & 1;
    const int msk2 = (q0 << 1) | q1;        // owned gate (0:i 2:g 1:f 3:o map)
    const int b0  = blockIdx.x * 2;

    __shared__ __align__(16) float he[2][64];
    __shared__ __align__(16) float hb[2][2 * 148];  // [buf][row*148 + (j>>5)*36 + (j&31)]

    if (tid < 128) he[tid >> 6][tid & 63] = h_enc[(size_t)(b0 + (tid >> 6)) * 64 + (tid & 63)];
    if (tid < 296) hb[0][tid] = 0.f;

    // recurrent weights: slot m -> gate row (m ^ msk2), cols [32q, 32q+32)
    f32x4 w[4][8];
    #pragma unroll
    for (int m = 0; m < 4; ++m) {
        const float* src = Whh + (size_t)((m ^ msk2) * 128 + gg) * 128 + 32 * q;
        #pragma unroll
        for (int c = 0; c < 8; ++c) w[m][c] = *(const f32x4*)(src + 4 * c);
    }

    const float sA = (msk2 == 2) ? 2.f : 1.f;
    const float sC = (msk2 == 2) ? -1.f : 0.f;
    const float nsA = -LOG2E * sA;
    const bool writer = (q == 0);
    const int kres = 36 * q;
    const int pj   = (gg >> 5) * 36 + (gg & 31);

    __syncthreads();

    // xp = bias + Wih_d . h_enc, both rows (time-invariant)
    float xpA, xpB;
    {
        const float* h0 = he[0] + 16 * q;
        const float* h1 = he[1] + 16 * q;
        f32x4 a0 = *(const f32x4*)h0, a1 = *(const f32x4*)(h0 + 4);
        f32x4 a2 = *(const f32x4*)(h0 + 8), a3 = *(const f32x4*)(h0 + 12);
        f32x4 b0v = *(const f32x4*)h1, b1v = *(const f32x4*)(h1 + 4);
        f32x4 b2v = *(const f32x4*)(h1 + 8), b3v = *(const f32x4*)(h1 + 12);
        float s[8];
        #pragma unroll
        for (int m = 0; m < 4; ++m) {
            const float* ws = Wih + (size_t)((m ^ msk2) * 128 + gg) * 64 + 16 * q;
            f32x4 w0 = *(const f32x4*)ws,       w1 = *(const f32x4*)(ws + 4);
            f32x4 w2 = *(const f32x4*)(ws + 8), w3 = *(const f32x4*)(ws + 12);
            float aA = 0.f, aB = 0.f;
            aA = fmaf(w0.x, a0.x, aA); aA = fmaf(w0.y, a0.y, aA);
            aA = fmaf(w0.z, a0.z, aA); aA = fmaf(w0.w, a0.w, aA);
            aA = fmaf(w1.x, a1.x, aA); aA = fmaf(w1.y, a1.y, aA);
            aA = fmaf(w1.z, a1.z, aA); aA = fmaf(w1.w, a1.w, aA);
            aA = fmaf(w2.x, a2.x, aA); aA = fmaf(w2.y, a2.y, aA);
            aA = fmaf(w2.z, a2.z, aA); aA = fmaf(w2.w, a2.w, aA);
            aA = fmaf(w3.x, a3.x, aA); aA = fmaf(w3.y, a3.y, aA);
            aA = fmaf(w3.z, a3.z, aA); aA = fmaf(w3.w, a3.w, aA);
            aB = fmaf(w0.x, b0v.x, aB); aB = fmaf(w0.y, b0v.y, aB);
            aB = fmaf(w0.z, b0v.z, aB); aB = fmaf(w0.w, b0v.w, aB);
            aB = fmaf(w1.x, b1v.x, aB); aB = fmaf(w1.y, b1v.y, aB);
            aB = fmaf(w1.z, b1v.z, aB); aB = fmaf(w1.w, b1v.w, aB);
            aB = fmaf(w2.x, b2v.x, aB); aB = fmaf(w2.y, b2v.y, aB);
            aB = fmaf(w2.z, b2v.z, aB); aB = fmaf(w2.w, b2v.w, aB);
            aB = fmaf(w3.x, b3v.x, aB); aB = fmaf(w3.y, b3v.y, aB);
            aB = fmaf(w3.z, b3v.z, aB); aB = fmaf(w3.w, b3v.w, aB);
            s[2 * m]     = aA;
            s[2 * m + 1] = aB;
        }
        s[0] += dpp_mov<0xB1>(s[4]); s[1] += dpp_mov<0xB1>(s[5]);
        s[2] += dpp_mov<0xB1>(s[6]); s[3] += dpp_mov<0xB1>(s[7]);
        s[0] += dpp_mov<0x4E>(s[2]); s[1] += dpp_mov<0x4E>(s[3]);
        const float bb = bias[msk2 * 128 + gg];
        xpA = s[0] + bb;
        xpB = s[1] + bb;
    }

    float cA = 0.f, cB = 0.f;
    size_t optrA = ((size_t)(b0 + 0) * TT) * 128 + gg;
    size_t optrB = ((size_t)(b0 + 1) * TT) * 128 + gg;

#define DSTEP(CUR, NXT) {                                                      \
    const float* p0 = (CUR) + kres;                                            \
    const float* p1 = (CUR) + 148 + kres;                                      \
    f32x4 ch0[8], ch1[8];                                                      \
    _Pragma("unroll") for (int c = 0; c < 8; ++c) ch0[c] = *(const f32x4*)(p0 + 4 * c); \
    _Pragma("unroll") for (int c = 0; c < 8; ++c) ch1[c] = *(const f32x4*)(p1 + 4 * c); \
    float s[8];                                                                \
    _Pragma("unroll") for (int m = 0; m < 4; ++m) { float a = 0.f;             \
        _Pragma("unroll") for (int c = 0; c < 8; ++c) {                        \
            a = fmaf(w[m][c].x, ch0[c].x, a); a = fmaf(w[m][c].y, ch0[c].y, a);\
            a = fmaf(w[m][c].z, ch0[c].z, a); a = fmaf(w[m][c].w, ch0[c].w, a);}\
        s[2 * m] = a; }                                                        \
    _Pragma("unroll") for (int m = 0; m < 4; ++m) { float a = 0.f;             \
        _Pragma("unroll") for (int c = 0; c < 8; ++c) {                        \
            a = fmaf(w[m][c].x, ch1[c].x, a); a = fmaf(w[m][c].y, ch1[c].y, a);\
            a = fmaf(w[m][c].z, ch1[c].z, a); a = fmaf(w[m][c].w, ch1[c].w, a);}\
        s[2 * m + 1] = a; }                                                    \
    s[0] += dpp_mov<0xB1>(s[4]); s[1] += dpp_mov<0xB1>(s[5]);                  \
    s[2] += dpp_mov<0xB1>(s[6]); s[3] += dpp_mov<0xB1>(s[7]);                  \
    s[0] += dpp_mov<0x4E>(s[2]); s[1] += dpp_mov<0x4E>(s[3]);                  \
    float zA = s[0] + xpA;                                                     \
    float zB = s[1] + xpB;                                                     \
    float ezA = __builtin_amdgcn_exp2f(zA * nsA);                              \
    float vA  = fmaf(__builtin_amdgcn_rcpf(1.0f + ezA), sA, sC);               \
    float ezB = __builtin_amdgcn_exp2f(zB * nsA);                              \
    float vB  = fmaf(__builtin_amdgcn_rcpf(1.0f + ezB), sA, sC);               \
    float viA = dpp_mov<0x00>(vA); float vgA = dpp_mov<0x55>(vA);              \
    float vfA = dpp_mov<0xAA>(vA); float voA = dpp_mov<0xFF>(vA);              \
    float viB = dpp_mov<0x00>(vB); float vgB = dpp_mov<0x55>(vB);              \
    float vfB = dpp_mov<0xAA>(vB); float voB = dpp_mov<0xFF>(vB);              \
    cA = fmaf(vfA, cA, viA * vgA);                                             \
    cB = fmaf(vfB, cB, viB * vgB);                                             \
    float e2A = __builtin_amdgcn_exp2f(cA * NEG2LOG2E);                        \
    float hvA = voA * fmaf(__builtin_amdgcn_rcpf(1.f + e2A), 2.f, -1.f);       \
    float e2B = __builtin_amdgcn_exp2f(cB * NEG2LOG2E);                        \
    float hvB = voB * fmaf(__builtin_amdgcn_rcpf(1.f + e2B), 2.f, -1.f);       \
    if (writer) {                                                              \
        (NXT)[pj] = hvA; (NXT)[148 + pj] = hvB;                                \
        out[optrA] = hvA; out[optrB] = hvB;                                    \
    }                                                                          \
    optrA += 128; optrB += 128;                                                \
    __syncthreads(); }

    #pragma unroll 1
    for (int t = 0; t < TT; t += 2) {
        DSTEP(hb[0], hb[1]);
        DSTEP(hb[1], hb[0]);
    }
#undef DSTEP
}

// ---------------------------------------------------------------------------
// Encoder: 256 blocks x 512 threads, 2 batch rows/block.  (unchanged from r3
// to isolate the dec delta.)
// ---------------------------------------------------------------------------
__global__ __launch_bounds__(512, 2)
void enc_kernel(const float* __restrict__ x,      // [B,T,128]
                const float* __restrict__ Wih,    // [256,128]
                const float* __restrict__ Whh,    // [256,64]
                const float* __restrict__ bias,   // [256]
                float* __restrict__ h_out)        // [B,64]
{
    const int tid = threadIdx.x;
    const int gg  = tid >> 3;               // j in [0,64)
    const int q   = tid & 7;
    const int q0 = q & 1, q1 = (q >> 1) & 1, q2 = (q >> 2) & 1;
    const int msk2 = (q0 << 1) | q1;
    const int b0  = blockIdx.x * 2;

    __shared__ __align__(16) float xh[2][2 * 224];  // [buf][row*224 + padded k]

    f32x4 w[4][6];
    #pragma unroll
    for (int m = 0; m < 4; ++m) {
        int row = (m ^ msk2) * 64 + gg;
        #pragma unroll
        for (int c = 0; c < 6; ++c) {
            int k0 = 24 * q + 4 * c;
            const float* src = (k0 < 128) ? (Wih + (size_t)row * 128 + k0)
                                          : (Whh + (size_t)row * 64 + (k0 - 128));
            w[m][c] = *(const f32x4*)src;
        }
    }

    const int t4own = 2 * q0 + q1;
    const float sA = (t4own == 2) ? 2.f : 1.f;
    const float sC = (t4own == 2) ? -1.f : 0.f;
    const float nsA = -LOG2E * sA;
    const bool writer = (q0 == 0) && (q1 == 0);
    const int rr  = q2;
    const int oA  = q2 * 224;
    const int oB  = (q2 ^ 1) * 224;
    const int kres = 28 * q;
    const int hj  = 128 + gg;
    const int pwj = q2 * 224 + hj + 4 * (hj / 24);
    const float xpc = bias[t4own * 64 + gg];

    const bool stager = (tid < 64);
    const int sr = (tid >> 5) & 1, sc = tid & 31;
    const int psl = sr * 224 + 4 * sc + 4 * ((4 * sc) / 24);
    const float* xbase = x + ((size_t)(b0 + sr) * TT) * 128 + 4 * sc;

    if (stager) *(f32x4*)(&xh[0][psl]) = *(const f32x4*)xbase;
    if (tid < 128) {
        int r = tid >> 6, j = 128 + (tid & 63);
        xh[0][r * 224 + j + 4 * (j / 24)] = 0.f;
    }

    float c_state = 0.f;
    float h_last = 0.f;
    __syncthreads();

#define ESTEP(CUR, NXT, T) {                                                   \
    f32x4 xnext;                                                               \
    if (stager) { int tl = (T) + 1 < TT ? (T) + 1 : TT - 1;                    \
        xnext = *(const f32x4*)(xbase + (size_t)tl * 128); }                   \
    const float* bAp = (CUR) + oA + kres;                                      \
    const float* bBp = (CUR) + oB + kres;                                      \
    f32x4 ch[6]; float s[8];                                                   \
    _Pragma("unroll") for (int c = 0; c < 6; ++c) ch[c] = *(const f32x4*)(bAp + 4 * c); \
    _Pragma("unroll") for (int m = 0; m < 4; ++m) { float a = 0.f;             \
        _Pragma("unroll") for (int c = 0; c < 6; ++c) {                        \
            a = fmaf(w[m][c].x, ch[c].x, a); a = fmaf(w[m][c].y, ch[c].y, a);  \
            a = fmaf(w[m][c].z, ch[c].z, a); a = fmaf(w[m][c].w, ch[c].w, a); }\
        s[2 * m] = a; }                                                        \
    _Pragma("unroll") for (int c = 0; c < 6; ++c) ch[c] = *(const f32x4*)(bBp + 4 * c); \
    _Pragma("unroll") for (int m = 0; m < 4; ++m) { float a = 0.f;             \
        _Pragma("unroll") for (int c = 0; c < 6; ++c) {                        \
            a = fmaf(w[m][c].x, ch[c].x, a); a = fmaf(w[m][c].y, ch[c].y, a);  \
            a = fmaf(w[m][c].z, ch[c].z, a); a = fmaf(w[m][c].w, ch[c].w, a); }\
        s[2 * m + 1] = a; }                                                    \
    float z = merge8(s) + xpc;                                                 \
    float ez = __builtin_amdgcn_exp2f(z * nsA);                                \
    float v  = fmaf(__builtin_amdgcn_rcpf(1.0f + ez), sA, sC);                 \
    float vi = dpp_mov<0x00>(v); float vg = dpp_mov<0x55>(v);                  \
    float vf = dpp_mov<0xAA>(v); float vo = dpp_mov<0xFF>(v);                  \
    c_state = fmaf(vf, c_state, vi * vg);                                      \
    float e2 = __builtin_amdgcn_exp2f(c_state * NEG2LOG2E);                    \
    float hv = vo * fmaf(__builtin_amdgcn_rcpf(1.f + e2), 2.f, -1.f);          \
    h_last = hv;                                                               \
    if (writer) (NXT)[pwj] = hv;                                               \
    if (stager) *(f32x4*)((NXT) + psl) = xnext;                                \
    __syncthreads(); }

    #pragma unroll 1
    for (int t = 0; t < TT; t += 2) {
        ESTEP(xh[0], xh[1], t);
        ESTEP(xh[1], xh[0], t + 1);
    }
#undef ESTEP

    if (writer) h_out[(size_t)(b0 + rr) * 64 + gg] = h_last;
}

extern "C" void kernel_launch(void* const* d_in, const int* in_sizes, int n_in,
                              void* d_out, int out_size, void* d_ws, size_t ws_size,
                              hipStream_t stream) {
    const float* x     = (const float*)d_in[0];
    const float* Wih_e = (const float*)d_in[1];
    const float* Whh_e = (const float*)d_in[2];
    const float* b_e   = (const float*)d_in[3];
    const float* Wih_d = (const float*)d_in[4];
    const float* Whh_d = (const float*)d_in[5];
    const float* b_d   = (const float*)d_in[6];
    float* out   = (float*)d_out;
    float* h_enc = (float*)d_ws;

    enc_kernel<<<dim3(256), dim3(512), 0, stream>>>(x, Wih_e, Whh_e, b_e, h_enc);
    dec_kernel<<<dim3(256), dim3(512), 0, stream>>>(h_enc, Wih_d, Whh_d, b_d, out);
}

// Round 5
// 988.758 us; speedup vs baseline: 1.0470x; 1.0470x over previous
//
#include <hip/hip_runtime.h>

#define TT 512

typedef float f32x4 __attribute__((ext_vector_type(4)));

template<int CTRL>
__device__ __forceinline__ float dpp_mov(float v) {
    return __int_as_float(__builtin_amdgcn_mov_dpp(__float_as_int(v), CTRL, 0xF, 0xF, true));
}
__device__ __forceinline__ float swz_xor4(float v) {
    return __int_as_float(__builtin_amdgcn_ds_swizzle(__float_as_int(v), 0x101F));
}

#define LOG2E 1.4426950408889634f
#define NEG2LOG2E -2.8853900817779268f

// 8-slot select-free xor-merge (3 lane-bits) — used by dec.
__device__ __forceinline__ float merge8(float* s) {
    s[0] += dpp_mov<0xB1>(s[4]);
    s[1] += dpp_mov<0xB1>(s[5]);
    s[2] += dpp_mov<0xB1>(s[6]);
    s[3] += dpp_mov<0xB1>(s[7]);
    s[0] += dpp_mov<0x4E>(s[2]);
    s[1] += dpp_mov<0x4E>(s[3]);
    return s[0] + swz_xor4(s[1]);
}

// ---------------------------------------------------------------------------
// Decoder: r3 version verbatim (proven 532 us). 256 blocks x 1024 threads,
// 2 rows/block, 4 waves/SIMD phase-locked (bubble ~280 cyc — r4 proved 2
// waves/SIMD raises it to ~466, a net loss despite lower issue count).
// ---------------------------------------------------------------------------
__global__ __launch_bounds__(1024, 4)
void dec_kernel(const float* __restrict__ h_enc,  // [B,64]
                const float* __restrict__ Wih,    // [512,64]
                const float* __restrict__ Whh,    // [512,128]
                const float* __restrict__ bias,   // [512]
                float* __restrict__ out)          // [B,T,128]
{
    const int tid = threadIdx.x;
    const int gg  = tid >> 3;               // j
    const int q   = tid & 7;
    const int q0 = q & 1, q1 = (q >> 1) & 1, q2 = (q >> 2) & 1;
    const int msk2 = (q0 << 1) | q1;
    const int b0  = blockIdx.x * 2;

    __shared__ __align__(16) float he[2][64];
    __shared__ __align__(16) float hb[2][2 * 160];   // [buf][row*160 + padded j]

    if (tid < 128) he[tid >> 6][tid & 63] = h_enc[(size_t)(b0 + (tid >> 6)) * 64 + (tid & 63)];
    if (tid < 256) {
        int r = tid >> 7, j = tid & 127;
        hb[0][r * 160 + j + 4 * (j >> 4)] = 0.f;
    }

    // recurrent weights -> registers (slot-permuted rows: m ^ msk2)
    f32x4 w[4][4];
    #pragma unroll
    for (int m = 0; m < 4; ++m) {
        const float* src = Whh + (size_t)((m ^ msk2) * 128 + gg) * 128 + 16 * q;
        #pragma unroll
        for (int c = 0; c < 4; ++c) w[m][c] = *(const f32x4*)(src + 4 * c);
    }

    const int t4own = 2 * q0 + q1;
    const float sA = (t4own == 2) ? 2.f : 1.f;
    const float sC = (t4own == 2) ? -1.f : 0.f;
    const float nsA = -LOG2E * sA;          // exp2-folded sigmoid/tanh scale
    const bool writer = (q0 == 0) && (q1 == 0);
    const int rr  = q2;
    const int oA  = q2 * 160;
    const int oB  = (q2 ^ 1) * 160;
    const int kres = 20 * q;
    const int pwj = q2 * 160 + gg + 4 * (gg >> 4);

    __syncthreads();

    // xp = bias + Wih_d . h_enc (time-invariant; same permuted merge layout)
    float xp;
    {
        const float* heA = he[q2] + 8 * q;
        const float* heB = he[q2 ^ 1] + 8 * q;
        f32x4 hA0 = *(const f32x4*)heA, hA1 = *(const f32x4*)(heA + 4);
        f32x4 hB0 = *(const f32x4*)heB, hB1 = *(const f32x4*)(heB + 4);
        float s[8];
        #pragma unroll
        for (int m = 0; m < 4; ++m) {
            const float* ws = Wih + (size_t)((m ^ msk2) * 128 + gg) * 64 + 8 * q;
            f32x4 w0 = *(const f32x4*)ws, w1 = *(const f32x4*)(ws + 4);
            float aA = 0.f, aB = 0.f;
            aA = fmaf(w0.x, hA0.x, aA); aA = fmaf(w0.y, hA0.y, aA);
            aA = fmaf(w0.z, hA0.z, aA); aA = fmaf(w0.w, hA0.w, aA);
            aA = fmaf(w1.x, hA1.x, aA); aA = fmaf(w1.y, hA1.y, aA);
            aA = fmaf(w1.z, hA1.z, aA); aA = fmaf(w1.w, hA1.w, aA);
            aB = fmaf(w0.x, hB0.x, aB); aB = fmaf(w0.y, hB0.y, aB);
            aB = fmaf(w0.z, hB0.z, aB); aB = fmaf(w0.w, hB0.w, aB);
            aB = fmaf(w1.x, hB1.x, aB); aB = fmaf(w1.y, hB1.y, aB);
            aB = fmaf(w1.z, hB1.z, aB); aB = fmaf(w1.w, hB1.w, aB);
            s[2 * m]     = aA;
            s[2 * m + 1] = aB;
        }
        xp = merge8(s) + bias[t4own * 128 + gg];
    }

    float c_state = 0.f;
    size_t optr = ((size_t)(b0 + rr) * TT) * 128 + gg;

#define DSTEP(CUR, NXT) {                                                      \
    const float* bAp = (CUR) + oA + kres;                                      \
    const float* bBp = (CUR) + oB + kres;                                      \
    f32x4 ch[4]; float s[8];                                                   \
    _Pragma("unroll") for (int c = 0; c < 4; ++c) ch[c] = *(const f32x4*)(bAp + 4 * c); \
    _Pragma("unroll") for (int m = 0; m < 4; ++m) { float a = 0.f;             \
        _Pragma("unroll") for (int c = 0; c < 4; ++c) {                        \
            a = fmaf(w[m][c].x, ch[c].x, a); a = fmaf(w[m][c].y, ch[c].y, a);  \
            a = fmaf(w[m][c].z, ch[c].z, a); a = fmaf(w[m][c].w, ch[c].w, a); }\
        s[2 * m] = a; }                                                        \
    _Pragma("unroll") for (int c = 0; c < 4; ++c) ch[c] = *(const f32x4*)(bBp + 4 * c); \
    _Pragma("unroll") for (int m = 0; m < 4; ++m) { float a = 0.f;             \
        _Pragma("unroll") for (int c = 0; c < 4; ++c) {                        \
            a = fmaf(w[m][c].x, ch[c].x, a); a = fmaf(w[m][c].y, ch[c].y, a);  \
            a = fmaf(w[m][c].z, ch[c].z, a); a = fmaf(w[m][c].w, ch[c].w, a); }\
        s[2 * m + 1] = a; }                                                    \
    float z = merge8(s) + xp;                                                  \
    float ez = __builtin_amdgcn_exp2f(z * nsA);                                \
    float v  = fmaf(__builtin_amdgcn_rcpf(1.0f + ez), sA, sC);                 \
    float vi = dpp_mov<0x00>(v); float vg = dpp_mov<0x55>(v);                  \
    float vf = dpp_mov<0xAA>(v); float vo = dpp_mov<0xFF>(v);                  \
    c_state = fmaf(vf, c_state, vi * vg);                                      \
    float e2 = __builtin_amdgcn_exp2f(c_state * NEG2LOG2E);                    \
    float hv = vo * fmaf(__builtin_amdgcn_rcpf(1.f + e2), 2.f, -1.f);          \
    if (writer) { (NXT)[pwj] = hv; out[optr] = hv; }                           \
    optr += 128;                                                               \
    __syncthreads(); }

    #pragma unroll 1
    for (int t = 0; t < TT; t += 2) {
        DSTEP(hb[0], hb[1]);
        DSTEP(hb[1], hb[0]);
    }
#undef DSTEP
}

// ---------------------------------------------------------------------------
// Encoder (REWRITTEN): 512 blocks x 512 threads, ONE batch row per block,
// launch_bounds(512,4) -> 2 independent blocks/CU = 4 waves/SIMD with
// INDEPENDENT barriers (block A's barrier drain overlaps block B's FMAs).
// tid = gg*8 + q; gg = j in [0,64), q in [0,8) = 24-float k-slice over
// concat [x(128)|h(64)] = 192 (padded 28*q, conflict-free).
// 4 gate-slots per lane (96 FMA), 2-level quad_perm merge (q0,q1) + one
// swz_xor4 self-exchange for the k-half bit (q2). Single gate tail/lane.
// Weights: 4 gate-rows x 24k = 24 f32x4 = 96 VGPR; ch staged 3+3 to fit
// the 128-VGPR cap.
// ---------------------------------------------------------------------------
__global__ __launch_bounds__(512, 4)
void enc_kernel(const float* __restrict__ x,      // [B,T,128]
                const float* __restrict__ Wih,    // [256,128]
                const float* __restrict__ Whh,    // [256,64]
                const float* __restrict__ bias,   // [256]
                float* __restrict__ h_out)        // [B,64]
{
    const int tid = threadIdx.x;
    const int gg  = tid >> 3;               // j in [0,64)
    const int q   = tid & 7;                // k-slice id
    const int q0 = q & 1, q1 = (q >> 1) & 1;
    const int msk2 = (q0 << 1) | q1;        // owned gate after merge
    const int row = blockIdx.x;             // one batch row per block

    __shared__ __align__(16) float xh[2][224];   // [buf][padded k], single row

    // weights: slot m -> gate row (m ^ msk2), k-slice [24q, 24q+24)
    f32x4 w[4][6];
    #pragma unroll
    for (int m = 0; m < 4; ++m) {
        int wr = (m ^ msk2) * 64 + gg;
        #pragma unroll
        for (int c = 0; c < 6; ++c) {
            int k0 = 24 * q + 4 * c;
            const float* src = (k0 < 128) ? (Wih + (size_t)wr * 128 + k0)
                                          : (Whh + (size_t)wr * 64 + (k0 - 128));
            w[m][c] = *(const f32x4*)src;
        }
    }

    const float sA = (msk2 == 2) ? 2.f : 1.f;
    const float sC = (msk2 == 2) ? -1.f : 0.f;
    const float nsA = -LOG2E * sA;
    const bool writer = (q == 0);
    const int kres = 28 * q;
    const int hj  = 128 + gg;
    const int pwj = hj + 4 * (hj / 24);
    const float xpc = bias[msk2 * 64 + gg];

    const bool stager = (tid < 32);
    const int psl = 4 * tid + 4 * ((4 * tid) / 24);   // valid for stagers
    const float* xbase = x + (size_t)row * TT * 128 + 4 * tid;

    if (stager) *(f32x4*)(&xh[0][psl]) = *(const f32x4*)xbase;
    if (tid < 64) {
        int j = 128 + tid;
        xh[0][j + 4 * (j / 24)] = 0.f;
    }

    float c_state = 0.f;
    float h_last = 0.f;
    __syncthreads();

#define ESTEP(CUR, NXT, T) {                                                   \
    f32x4 xnext;                                                               \
    if (stager) { int tl = (T) + 1 < TT ? (T) + 1 : TT - 1;                    \
        xnext = *(const f32x4*)(xbase + (size_t)tl * 128); }                   \
    const float* bp = (CUR) + kres;                                            \
    float s[4];                                                                \
    {   /* first k-half: c = 0..2 (staged to bound VGPR pressure) */           \
        f32x4 c0 = *(const f32x4*)(bp), c1 = *(const f32x4*)(bp + 4),          \
              c2 = *(const f32x4*)(bp + 8);                                    \
        _Pragma("unroll") for (int m = 0; m < 4; ++m) { float a = 0.f;         \
            a = fmaf(w[m][0].x, c0.x, a); a = fmaf(w[m][0].y, c0.y, a);        \
            a = fmaf(w[m][0].z, c0.z, a); a = fmaf(w[m][0].w, c0.w, a);        \
            a = fmaf(w[m][1].x, c1.x, a); a = fmaf(w[m][1].y, c1.y, a);        \
            a = fmaf(w[m][1].z, c1.z, a); a = fmaf(w[m][1].w, c1.w, a);        \
            a = fmaf(w[m][2].x, c2.x, a); a = fmaf(w[m][2].y, c2.y, a);        \
            a = fmaf(w[m][2].z, c2.z, a); a = fmaf(w[m][2].w, c2.w, a);        \
            s[m] = a; }                                                        \
    }                                                                          \
    {   /* second k-half: c = 3..5 */                                          \
        f32x4 c0 = *(const f32x4*)(bp + 12), c1 = *(const f32x4*)(bp + 16),    \
              c2 = *(const f32x4*)(bp + 20);                                   \
        _Pragma("unroll") for (int m = 0; m < 4; ++m) { float a = s[m];        \
            a = fmaf(w[m][3].x, c0.x, a); a = fmaf(w[m][3].y, c0.y, a);        \
            a = fmaf(w[m][3].z, c0.z, a); a = fmaf(w[m][3].w, c0.w, a);        \
            a = fmaf(w[m][4].x, c1.x, a); a = fmaf(w[m][4].y, c1.y, a);        \
            a = fmaf(w[m][4].z, c1.z, a); a = fmaf(w[m][4].w, c1.w, a);        \
            a = fmaf(w[m][5].x, c2.x, a); a = fmaf(w[m][5].y, c2.y, a);        \
            a = fmaf(w[m][5].z, c2.z, a); a = fmaf(w[m][5].w, c2.w, a);        \
            s[m] = a; }                                                        \
    }                                                                          \
    /* 2-level merge over q0,q1 (slot-weight: q0->2, q1->1), then q2 half */   \
    s[0] += dpp_mov<0xB1>(s[2]); s[1] += dpp_mov<0xB1>(s[3]);                  \
    s[0] += dpp_mov<0x4E>(s[1]);                                               \
    float z = s[0] + swz_xor4(s[0]) + xpc;                                     \
    float ez = __builtin_amdgcn_exp2f(z * nsA);                                \
    float v  = fmaf(__builtin_amdgcn_rcpf(1.0f + ez), sA, sC);                 \
    float vi = dpp_mov<0x00>(v); float vg = dpp_mov<0x55>(v);                  \
    float vf = dpp_mov<0xAA>(v); float vo = dpp_mov<0xFF>(v);                  \
    c_state = fmaf(vf, c_state, vi * vg);                                      \
    float e2 = __builtin_amdgcn_exp2f(c_state * NEG2LOG2E);                    \
    float hv = vo * fmaf(__builtin_amdgcn_rcpf(1.f + e2), 2.f, -1.f);          \
    h_last = hv;                                                               \
    if (writer) (NXT)[pwj] = hv;                                               \
    if (stager) *(f32x4*)((NXT) + psl) = xnext;                                \
    __syncthreads(); }

    #pragma unroll 1
    for (int t = 0; t < TT; t += 2) {
        ESTEP(xh[0], xh[1], t);
        ESTEP(xh[1], xh[0], t + 1);
    }
#undef ESTEP

    if (writer) h_out[(size_t)row * 64 + gg] = h_last;
}

extern "C" void kernel_launch(void* const* d_in, const int* in_sizes, int n_in,
                              void* d_out, int out_size, void* d_ws, size_t ws_size,
                              hipStream_t stream) {
    const float* x     = (const float*)d_in[0];
    const float* Wih_e = (const float*)d_in[1];
    const float* Whh_e = (const float*)d_in[2];
    const float* b_e   = (const float*)d_in[3];
    const float* Wih_d = (const float*)d_in[4];
    const float* Whh_d = (const float*)d_in[5];
    const float* b_d   = (const float*)d_in[6];
    float* out   = (float*)d_out;
    float* h_enc = (float*)d_ws;

    enc_kernel<<<dim3(512), dim3(512), 0, stream>>>(x, Wih_e, Whh_e, b_e, h_enc);
    dec_kernel<<<dim3(256), dim3(1024), 0, stream>>>(h_enc, Wih_d, Whh_d, b_d, out);
}

// Round 7
// 981.661 us; speedup vs baseline: 1.0545x; 1.0072x over previous
//
#include <hip/hip_runtime.h>

#define TT 512

typedef float f32x4 __attribute__((ext_vector_type(4)));

template<int CTRL>
__device__ __forceinline__ float dpp_mov(float v) {
    return __int_as_float(__builtin_amdgcn_mov_dpp(__float_as_int(v), CTRL, 0xF, 0xF, true));
}
__device__ __forceinline__ float swz_xor4(float v) {
    return __int_as_float(__builtin_amdgcn_ds_swizzle(__float_as_int(v), 0x101F));
}

#define LOG2E 1.4426950408889634f
#define NEG2LOG2E -2.8853900817779268f

// 8-slot select-free xor-merge (3 lane-bits) — used by dec.
__device__ __forceinline__ float merge8(float* s) {
    s[0] += dpp_mov<0xB1>(s[4]);
    s[1] += dpp_mov<0xB1>(s[5]);
    s[2] += dpp_mov<0xB1>(s[6]);
    s[3] += dpp_mov<0xB1>(s[7]);
    s[0] += dpp_mov<0x4E>(s[2]);
    s[1] += dpp_mov<0x4E>(s[3]);
    return s[0] + swz_xor4(s[1]);
}

// ---------------------------------------------------------------------------
// Decoder: r3 version verbatim (proven 528-532 us). 256 blocks x 1024
// threads, 2 rows/block, 4 waves/SIMD phase-locked. Structurally pinned:
// 1-row blocks need 128 weight-regs/thread (Whh residency is conserved),
// which busts the 128-reg budget required for 2 blocks/CU. FMA floor is
// 1024 of the 1650 cyc/step.
// ---------------------------------------------------------------------------
__global__ __launch_bounds__(1024, 4)
void dec_kernel(const float* __restrict__ h_enc,  // [B,64]
                const float* __restrict__ Wih,    // [512,64]
                const float* __restrict__ Whh,    // [512,128]
                const float* __restrict__ bias,   // [512]
                float* __restrict__ out)          // [B,T,128]
{
    const int tid = threadIdx.x;
    const int gg  = tid >> 3;               // j
    const int q   = tid & 7;
    const int q0 = q & 1, q1 = (q >> 1) & 1, q2 = (q >> 2) & 1;
    const int msk2 = (q0 << 1) | q1;
    const int b0  = blockIdx.x * 2;

    __shared__ __align__(16) float he[2][64];
    __shared__ __align__(16) float hb[2][2 * 160];   // [buf][row*160 + padded j]

    if (tid < 128) he[tid >> 6][tid & 63] = h_enc[(size_t)(b0 + (tid >> 6)) * 64 + (tid & 63)];
    if (tid < 256) {
        int r = tid >> 7, j = tid & 127;
        hb[0][r * 160 + j + 4 * (j >> 4)] = 0.f;
    }

    // recurrent weights -> registers (slot-permuted rows: m ^ msk2)
    f32x4 w[4][4];
    #pragma unroll
    for (int m = 0; m < 4; ++m) {
        const float* src = Whh + (size_t)((m ^ msk2) * 128 + gg) * 128 + 16 * q;
        #pragma unroll
        for (int c = 0; c < 4; ++c) w[m][c] = *(const f32x4*)(src + 4 * c);
    }

    const int t4own = 2 * q0 + q1;
    const float sA = (t4own == 2) ? 2.f : 1.f;
    const float sC = (t4own == 2) ? -1.f : 0.f;
    const float nsA = -LOG2E * sA;          // exp2-folded sigmoid/tanh scale
    const bool writer = (q0 == 0) && (q1 == 0);
    const int rr  = q2;
    const int oA  = q2 * 160;
    const int oB  = (q2 ^ 1) * 160;
    const int kres = 20 * q;
    const int pwj = q2 * 160 + gg + 4 * (gg >> 4);

    __syncthreads();

    // xp = bias + Wih_d . h_enc (time-invariant; same permuted merge layout)
    float xp;
    {
        const float* heA = he[q2] + 8 * q;
        const float* heB = he[q2 ^ 1] + 8 * q;
        f32x4 hA0 = *(const f32x4*)heA, hA1 = *(const f32x4*)(heA + 4);
        f32x4 hB0 = *(const f32x4*)heB, hB1 = *(const f32x4*)(heB + 4);
        float s[8];
        #pragma unroll
        for (int m = 0; m < 4; ++m) {
            const float* ws = Wih + (size_t)((m ^ msk2) * 128 + gg) * 64 + 8 * q;
            f32x4 w0 = *(const f32x4*)ws, w1 = *(const f32x4*)(ws + 4);
            float aA = 0.f, aB = 0.f;
            aA = fmaf(w0.x, hA0.x, aA); aA = fmaf(w0.y, hA0.y, aA);
            aA = fmaf(w0.z, hA0.z, aA); aA = fmaf(w0.w, hA0.w, aA);
            aA = fmaf(w1.x, hA1.x, aA); aA = fmaf(w1.y, hA1.y, aA);
            aA = fmaf(w1.z, hA1.z, aA); aA = fmaf(w1.w, hA1.w, aA);
            aB = fmaf(w0.x, hB0.x, aB); aB = fmaf(w0.y, hB0.y, aB);
            aB = fmaf(w0.z, hB0.z, aB); aB = fmaf(w0.w, hB0.w, aB);
            aB = fmaf(w1.x, hB1.x, aB); aB = fmaf(w1.y, hB1.y, aB);
            aB = fmaf(w1.z, hB1.z, aB); aB = fmaf(w1.w, hB1.w, aB);
            s[2 * m]     = aA;
            s[2 * m + 1] = aB;
        }
        xp = merge8(s) + bias[t4own * 128 + gg];
    }

    float c_state = 0.f;
    size_t optr = ((size_t)(b0 + rr) * TT) * 128 + gg;

#define DSTEP(CUR, NXT) {                                                      \
    const float* bAp = (CUR) + oA + kres;                                      \
    const float* bBp = (CUR) + oB + kres;                                      \
    f32x4 ch[4]; float s[8];                                                   \
    _Pragma("unroll") for (int c = 0; c < 4; ++c) ch[c] = *(const f32x4*)(bAp + 4 * c); \
    _Pragma("unroll") for (int m = 0; m < 4; ++m) { float a = 0.f;             \
        _Pragma("unroll") for (int c = 0; c < 4; ++c) {                        \
            a = fmaf(w[m][c].x, ch[c].x, a); a = fmaf(w[m][c].y, ch[c].y, a);  \
            a = fmaf(w[m][c].z, ch[c].z, a); a = fmaf(w[m][c].w, ch[c].w, a); }\
        s[2 * m] = a; }                                                        \
    _Pragma("unroll") for (int c = 0; c < 4; ++c) ch[c] = *(const f32x4*)(bBp + 4 * c); \
    _Pragma("unroll") for (int m = 0; m < 4; ++m) { float a = 0.f;             \
        _Pragma("unroll") for (int c = 0; c < 4; ++c) {                        \
            a = fmaf(w[m][c].x, ch[c].x, a); a = fmaf(w[m][c].y, ch[c].y, a);  \
            a = fmaf(w[m][c].z, ch[c].z, a); a = fmaf(w[m][c].w, ch[c].w, a); }\
        s[2 * m + 1] = a; }                                                    \
    float z = merge8(s) + xp;                                                  \
    float ez = __builtin_amdgcn_exp2f(z * nsA);                                \
    float v  = fmaf(__builtin_amdgcn_rcpf(1.0f + ez), sA, sC);                 \
    float vi = dpp_mov<0x00>(v); float vg = dpp_mov<0x55>(v);                  \
    float vf = dpp_mov<0xAA>(v); float vo = dpp_mov<0xFF>(v);                  \
    c_state = fmaf(vf, c_state, vi * vg);                                      \
    float e2 = __builtin_amdgcn_exp2f(c_state * NEG2LOG2E);                    \
    float hv = vo * fmaf(__builtin_amdgcn_rcpf(1.f + e2), 2.f, -1.f);          \
    if (writer) { (NXT)[pwj] = hv; out[optr] = hv; }                           \
    optr += 128;                                                               \
    __syncthreads(); }

    #pragma unroll 1
    for (int t = 0; t < TT; t += 2) {
        DSTEP(hb[0], hb[1]);
        DSTEP(hb[1], hb[0]);
    }
#undef DSTEP
}

// ---------------------------------------------------------------------------
// Encoder: 512 blocks x 512 threads, ONE row per block, 2 independent
// blocks/CU (r5 structure) + deliberate anti-phase between the two
// co-resident blocks. Both blocks have identical per-step periods, so
// without a forced offset they run phase-locked and their serial spines
// (merge -> trans chain -> ds_write -> barrier -> 120cy ds_read) coincide,
// wasting the cross-block overlap the structure was built for. Odd-phase
// blocks run a ~700-cycle dependent-FMA delay before the loop; the offset
// persists (no cross-block resync). phase = (bid ^ bid>>8) & 1 covers both
// plausible co-residency patterns (consecutive pairs and b/b+256 pairs).
// (r6 bench was an infra failure — resubmitted unchanged for a clean A/B
// against r5's 988.8 us.)
// ---------------------------------------------------------------------------
__global__ __launch_bounds__(512, 4)
void enc_kernel(const float* __restrict__ x,      // [B,T,128]
                const float* __restrict__ Wih,    // [256,128]
                const float* __restrict__ Whh,    // [256,64]
                const float* __restrict__ bias,   // [256]
                float* __restrict__ h_out)        // [B,64]
{
    const int tid = threadIdx.x;
    const int gg  = tid >> 3;               // j in [0,64)
    const int q   = tid & 7;                // k-slice id
    const int q0 = q & 1, q1 = (q >> 1) & 1;
    const int msk2 = (q0 << 1) | q1;        // owned gate after merge
    const int row = blockIdx.x;             // one batch row per block

    __shared__ __align__(16) float xh[2][224];   // [buf][padded k], single row

    // weights: slot m -> gate row (m ^ msk2), k-slice [24q, 24q+24)
    f32x4 w[4][6];
    #pragma unroll
    for (int m = 0; m < 4; ++m) {
        int wr = (m ^ msk2) * 64 + gg;
        #pragma unroll
        for (int c = 0; c < 6; ++c) {
            int k0 = 24 * q + 4 * c;
            const float* src = (k0 < 128) ? (Wih + (size_t)wr * 128 + k0)
                                          : (Whh + (size_t)wr * 64 + (k0 - 128));
            w[m][c] = *(const f32x4*)src;
        }
    }

    const float sA = (msk2 == 2) ? 2.f : 1.f;
    const float sC = (msk2 == 2) ? -1.f : 0.f;
    const float nsA = -LOG2E * sA;
    const bool writer = (q == 0);
    const int kres = 28 * q;
    const int hj  = 128 + gg;
    const int pwj = hj + 4 * (hj / 24);
    const float xpc = bias[msk2 * 64 + gg];

    const bool stager = (tid < 32);
    const int psl = 4 * tid + 4 * ((4 * tid) / 24);   // valid for stagers
    const float* xbase = x + (size_t)row * TT * 128 + 4 * tid;

    if (stager) *(f32x4*)(&xh[0][psl]) = *(const f32x4*)xbase;
    if (tid < 64) {
        int j = 128 + tid;
        xh[0][j + 4 * (j / 24)] = 0.f;
    }

    // Anti-phase delay: ~175 dependent FMAs (~700 cyc at 4 cyc dep latency).
    // Block-uniform branch; result kept alive via asm so it can't be elided.
    if (((blockIdx.x ^ (blockIdx.x >> 8)) & 1) != 0) {
        float d = xpc + (float)tid * 1e-12f;
        #pragma unroll 1
        for (int i = 0; i < 35; ++i) {
            d = fmaf(d, 1.0000001f, 1.1920929e-07f);
            d = fmaf(d, 1.0000001f, 1.1920929e-07f);
            d = fmaf(d, 1.0000001f, 1.1920929e-07f);
            d = fmaf(d, 1.0000001f, 1.1920929e-07f);
            d = fmaf(d, 1.0000001f, 1.1920929e-07f);
        }
        asm volatile("" :: "v"(d));
    }

    float c_state = 0.f;
    float h_last = 0.f;
    __syncthreads();

#define ESTEP(CUR, NXT, T) {                                                   \
    f32x4 xnext;                                                               \
    if (stager) { int tl = (T) + 1 < TT ? (T) + 1 : TT - 1;                    \
        xnext = *(const f32x4*)(xbase + (size_t)tl * 128); }                   \
    const float* bp = (CUR) + kres;                                            \
    float s[4];                                                                \
    {   /* first k-half: c = 0..2 (staged to bound VGPR pressure) */           \
        f32x4 c0 = *(const f32x4*)(bp), c1 = *(const f32x4*)(bp + 4),          \
              c2 = *(const f32x4*)(bp + 8);                                    \
        _Pragma("unroll") for (int m = 0; m < 4; ++m) { float a = 0.f;         \
            a = fmaf(w[m][0].x, c0.x, a); a = fmaf(w[m][0].y, c0.y, a);        \
            a = fmaf(w[m][0].z, c0.z, a); a = fmaf(w[m][0].w, c0.w, a);        \
            a = fmaf(w[m][1].x, c1.x, a); a = fmaf(w[m][1].y, c1.y, a);        \
            a = fmaf(w[m][1].z, c1.z, a); a = fmaf(w[m][1].w, c1.w, a);        \
            a = fmaf(w[m][2].x, c2.x, a); a = fmaf(w[m][2].y, c2.y, a);        \
            a = fmaf(w[m][2].z, c2.z, a); a = fmaf(w[m][2].w, c2.w, a);        \
            s[m] = a; }                                                        \
    }                                                                          \
    {   /* second k-half: c = 3..5 */                                          \
        f32x4 c0 = *(const f32x4*)(bp + 12), c1 = *(const f32x4*)(bp + 16),    \
              c2 = *(const f32x4*)(bp + 20);                                   \
        _Pragma("unroll") for (int m = 0; m < 4; ++m) { float a = s[m];        \
            a = fmaf(w[m][3].x, c0.x, a); a = fmaf(w[m][3].y, c0.y, a);        \
            a = fmaf(w[m][3].z, c0.z, a); a = fmaf(w[m][3].w, c0.w, a);        \
            a = fmaf(w[m][4].x, c1.x, a); a = fmaf(w[m][4].y, c1.y, a);        \
            a = fmaf(w[m][4].z, c1.z, a); a = fmaf(w[m][4].w, c1.w, a);        \
            a = fmaf(w[m][5].x, c2.x, a); a = fmaf(w[m][5].y, c2.y, a);        \
            a = fmaf(w[m][5].z, c2.z, a); a = fmaf(w[m][5].w, c2.w, a);        \
            s[m] = a; }                                                        \
    }                                                                          \
    /* 2-level merge over q0,q1 (slot-weight: q0->2, q1->1), then q2 half */   \
    s[0] += dpp_mov<0xB1>(s[2]); s[1] += dpp_mov<0xB1>(s[3]);                  \
    s[0] += dpp_mov<0x4E>(s[1]);                                               \
    float z = s[0] + swz_xor4(s[0]) + xpc;                                     \
    float ez = __builtin_amdgcn_exp2f(z * nsA);                                \
    float v  = fmaf(__builtin_amdgcn_rcpf(1.0f + ez), sA, sC);                 \
    float vi = dpp_mov<0x00>(v); float vg = dpp_mov<0x55>(v);                  \
    float vf = dpp_mov<0xAA>(v); float vo = dpp_mov<0xFF>(v);                  \
    c_state = fmaf(vf, c_state, vi * vg);                                      \
    float e2 = __builtin_amdgcn_exp2f(c_state * NEG2LOG2E);                    \
    float hv = vo * fmaf(__builtin_amdgcn_rcpf(1.f + e2), 2.f, -1.f);          \
    h_last = hv;                                                               \
    if (writer) (NXT)[pwj] = hv;                                               \
    if (stager) *(f32x4*)((NXT) + psl) = xnext;                                \
    __syncthreads(); }

    #pragma unroll 1
    for (int t = 0; t < TT; t += 2) {
        ESTEP(xh[0], xh[1], t);
        ESTEP(xh[1], xh[0], t + 1);
    }
#undef ESTEP

    if (writer) h_out[(size_t)row * 64 + gg] = h_last;
}

extern "C" void kernel_launch(void* const* d_in, const int* in_sizes, int n_in,
                              void* d_out, int out_size, void* d_ws, size_t ws_size,
                              hipStream_t stream) {
    const float* x     = (const float*)d_in[0];
    const float* Wih_e = (const float*)d_in[1];
    const float* Whh_e = (const float*)d_in[2];
    const float* b_e   = (const float*)d_in[3];
    const float* Wih_d = (const float*)d_in[4];
    const float* Whh_d = (const float*)d_in[5];
    const float* b_d   = (const float*)d_in[6];
    float* out   = (float*)d_out;
    float* h_enc = (float*)d_ws;

    enc_kernel<<<dim3(512), dim3(512), 0, stream>>>(x, Wih_e, Whh_e, b_e, h_enc);
    dec_kernel<<<dim3(256), dim3(1024), 0, stream>>>(h_enc, Wih_d, Whh_d, b_d, out);
}